// Round 21
// baseline (191.516 us; speedup 1.0000x reference)
//
#include <hip/hip_runtime.h>

typedef short bf16x8 __attribute__((ext_vector_type(8)));
typedef float f32x4 __attribute__((ext_vector_type(4)));

__device__ __forceinline__ ushort f2b(float f) {
  union { float f; unsigned u; } v; v.f = f;
  unsigned r = v.u + 0x7FFF + ((v.u >> 16) & 1);
  return (ushort)(r >> 16);
}
__device__ __forceinline__ float b2f(ushort u) {
  union { unsigned u; float f; } v; v.u = ((unsigned)u) << 16;
  return v.f;
}
__device__ __forceinline__ unsigned cvtpk(float lo, float hi) {
  unsigned r;
  asm volatile("v_cvt_pk_bf16_f32 %0, %1, %2" : "=v"(r) : "v"(lo), "v"(hi));
  return r;
}
__device__ __forceinline__ f32x4 mfma16(bf16x8 a, bf16x8 b, f32x4 c) {
  return __builtin_amdgcn_mfma_f32_16x16x32_bf16(a, b, c, 0, 0, 0);
}

#define GLD_LDS16(g, l) \
  __builtin_amdgcn_global_load_lds((const __attribute__((address_space(1))) void*)(g), \
                                   (__attribute__((address_space(3))) void*)(l), 16, 0, 0)

// ---------------- fused fp32 -> bf16 cast (float4 units; R8-verified) -------
__global__ __launch_bounds__(256) void cast_all(const float* __restrict__ x,
                                                const float* __restrict__ wq,
                                                const float* __restrict__ wk,
                                                const float* __restrict__ wv,
                                                const float* __restrict__ wo,
                                                ushort* __restrict__ xb,
                                                ushort* __restrict__ wqkvb,
                                                ushort* __restrict__ wob) {
  const long i = (long)blockIdx.x * 256 + threadIdx.x;  // float4 index
  const float* src;
  ushort* dst;
  long j;
  if (i < 2097152) {            // x: 2097152 float4
    src = x; j = i; dst = xb;
  } else if (i < 3145728) {     // Wq: 1048576 float4
    src = wq; j = i - 2097152; dst = wqkvb;
  } else if (i < 3407872) {     // Wk: 262144 float4
    src = wk; j = i - 3145728; dst = wqkvb + 4194304;
  } else if (i < 3670016) {     // Wv: 262144 float4
    src = wv; j = i - 3407872; dst = wqkvb + 5242880;
  } else {                      // Wo: 1048576 float4 (total 4718592)
    src = wo; j = i - 3670016; dst = wob;
  }
  float4 f = ((const float4*)src)[j];
  ushort4 u;
  u.x = f2b(f.x); u.y = f2b(f.y); u.z = f2b(f.z); u.w = f2b(f.w);
  ((ushort4*)dst)[j] = u;
}

// ---------------- RoPE tables ----------------
__global__ void rope_tables_k(float* __restrict__ cosT, float* __restrict__ sinT) {
  int s = blockIdx.x, i = threadIdx.x;  // 64 threads
  float inv = powf(10000.0f, -(float)i * (1.0f / 64.0f));
  float f = (float)s * inv;
  cosT[s * 64 + i] = cosf(f);
  sinT[s * 64 + i] = sinf(f);
}

// =================== 8-phase pipelined GEMM (T2+T3+T4+T5) ===================
template <int BM, int BN, bool BF16OUT>
__global__ __launch_bounds__(512, 2) void gemm8p(const ushort* __restrict__ A,
                                                 const ushort* __restrict__ B,
                                                 void* __restrict__ Cout,
                                                 int M, int N, int K) {
  constexpr int AF = BM / 64;
  constexpr int BF = BN / 64;
  constexpr int MFR = BM / 32;
  constexpr int LA = BM / 128;
  constexpr int LB = BN / 128;
  constexpr int ASZ = BM * 32;
  constexpr int BSZ = BN * 32;
  constexpr int VMN = LA + 2 * LB;
  __shared__ __align__(16) ushort lds[4 * (ASZ + BSZ)];
  const int t = threadIdx.x;
  const int lane = t & 63, w = t >> 6;
  const int wr = w & 1, wc = w >> 1;
  const int l15 = lane & 15, l4 = lane >> 4;
  const int nbn = N / BN;
  const int nwg = (int)gridDim.x;
  int bid = (int)blockIdx.x;
  bid = (bid & 7) * (nwg >> 3) + (bid >> 3);  // XCD swizzle (nwg % 8 == 0)
  const long m0 = (long)(bid / nbn) * BM;
  const long n0 = (long)(bid % nbn) * BN;
  const int nk = K >> 6;
  const int rdl = l15 * 32 + ((l4 ^ ((l15 >> 1) & 3)) * 8);  // swizzled read

  f32x4 acc[MFR][BF] = {};
  bf16x8 af[AF], bf[BF];

#define STA(tile, ks)                                                          \
  do {                                                                         \
    const int tt_ = (tile) < nk ? (tile) : nk - 1;                             \
    _Pragma("unroll") for (int c = 0; c < LA; ++c) {                           \
      const int us_ = t * 8 + c * 4096;                                        \
      const int r_ = us_ >> 5;                                                 \
      const int cs_ = (((us_ >> 3) & 3) ^ ((r_ >> 1) & 3)) * 8;                \
      GLD_LDS16(A + (m0 + r_) * K + tt_ * 64 + (ks) * 32 + cs_,                \
                &lds[(((tile) & 1) * 2 + (ks)) * ASZ + us_]);                  \
    }                                                                          \
  } while (0)
#define STB(tile, ks)                                                          \
  do {                                                                         \
    const int tt_ = (tile) < nk ? (tile) : nk - 1;                             \
    _Pragma("unroll") for (int c = 0; c < LB; ++c) {                           \
      const int us_ = t * 8 + c * 4096;                                        \
      const int r_ = us_ >> 5;                                                 \
      const int cs_ = (((us_ >> 3) & 3) ^ ((r_ >> 1) & 3)) * 8;                \
      GLD_LDS16(B + (n0 + r_) * K + tt_ * 64 + (ks) * 32 + cs_,                \
                &lds[4 * ASZ + (((tile) & 1) * 2 + (ks)) * BSZ + us_]);        \
    }                                                                          \
  } while (0)
#define LDA8(slot, ks, mq)                                                     \
  _Pragma("unroll") for (int a = 0; a < AF; ++a)                               \
      af[a] = *(const bf16x8*)(&lds[((slot) * 2 + (ks)) * ASZ +                \
                                    (wr * MFR + (mq) * AF + a) * 512 + rdl]);
#define LDB8(slot, ks)                                                         \
  _Pragma("unroll") for (int b = 0; b < BF; ++b)                               \
      bf[b] = *(const bf16x8*)(&lds[4 * ASZ + ((slot) * 2 + (ks)) * BSZ +      \
                                    (wc * BF + b) * 512 + rdl]);
#define VMW()                                                                  \
  do {                                                                         \
    if constexpr (VMN == 7)                                                    \
      asm volatile("s_waitcnt vmcnt(7)" ::: "memory");                         \
    else if constexpr (VMN == 6)                                               \
      asm volatile("s_waitcnt vmcnt(6)" ::: "memory");                         \
    else                                                                       \
      asm volatile("s_waitcnt vmcnt(5)" ::: "memory");                         \
  } while (0)
#define BARMM(mq)                                                              \
  do {                                                                         \
    __builtin_amdgcn_s_barrier();                                              \
    asm volatile("s_waitcnt lgkmcnt(0)" ::: "memory");                         \
    __builtin_amdgcn_sched_barrier(0);                                         \
    __builtin_amdgcn_s_setprio(1);                                             \
    _Pragma("unroll") for (int a = 0; a < AF; ++a)                             \
        _Pragma("unroll") for (int b = 0; b < BF; ++b)                         \
            acc[(mq) * AF + a][b] = mfma16(af[a], bf[b], acc[(mq) * AF + a][b]); \
    __builtin_amdgcn_s_setprio(0);                                             \
    __builtin_amdgcn_s_barrier();                                              \
  } while (0)

  STA(0, 0); STB(0, 0); STA(0, 1); STB(0, 1);
  STA(1, 0); STB(1, 0); STB(1, 1);
  VMW();
  __builtin_amdgcn_s_barrier();

  for (int i = 0; i < (nk >> 1); ++i) {
    const int t1 = 2 * i + 1, t2 = 2 * i + 2, t3 = 2 * i + 3;
    LDA8(0, 0, 0); LDB8(0, 0); STA(t1, 1);          BARMM(0);  // ph1
    LDA8(0, 0, 1);             STB(t2, 0);          BARMM(1);  // ph2
    LDA8(0, 1, 0); LDB8(0, 1); STA(t2, 0);          BARMM(0);  // ph3
    LDA8(0, 1, 1);             STB(t2, 1); VMW();   BARMM(1);  // ph4
    LDA8(1, 0, 0); LDB8(1, 0); STA(t2, 1);          BARMM(0);  // ph5
    LDA8(1, 0, 1);             STB(t3, 0);          BARMM(1);  // ph6
    LDA8(1, 1, 0); LDB8(1, 1); STA(t3, 0);          BARMM(0);  // ph7
    LDA8(1, 1, 1);             STB(t3, 1); VMW();   BARMM(1);  // ph8
  }
  asm volatile("s_waitcnt vmcnt(0)" ::: "memory");

#pragma unroll
  for (int m = 0; m < MFR; ++m) {
#pragma unroll
    for (int n = 0; n < BF; ++n) {
      long mrow = m0 + wr * (BM / 2) + m * 16 + l4 * 4;
      long ncol = n0 + wc * (BN / 4) + n * 16 + l15;
#pragma unroll
      for (int r = 0; r < 4; ++r) {
        if constexpr (BF16OUT)
          ((ushort*)Cout)[(mrow + r) * N + ncol] = f2b(acc[m][n][r]);
        else
          ((float*)Cout)[(mrow + r) * N + ncol] = acc[m][n][r];
      }
    }
  }
#undef STA
#undef STB
#undef LDA8
#undef LDB8
#undef VMW
#undef BARMM
}

// ---------------- RMSnorm + RoPE + layout (q,k) / cast+transpose (v) --------
__global__ __launch_bounds__(256) void postproc_k(const ushort* __restrict__ qkvb,
                                                  const float* __restrict__ cosT,
                                                  const float* __restrict__ sinT,
                                                  ushort* __restrict__ qb,
                                                  ushort* __restrict__ kb,
                                                  ushort* __restrict__ vtb) {
  const int lane = threadIdx.x & 63;
  const int s = blockIdx.x * 4 + (threadIdx.x >> 6);
  const int h = blockIdx.y;
  const int colbase = (h < 16) ? h * 128 : (h < 20 ? 2048 + (h - 16) * 128
                                                   : 2560 + (h - 20) * 128);
  const ushort* row = qkvb + (long)s * 3072 + colbase;
  float x1 = b2f(row[lane]), x2 = b2f(row[lane + 64]);
  if (h >= 20) {  // V: cast + transpose to [kvh][128][S-permuted]
    int kvh = h - 20;
    int spos = (s & ~31) | (((s >> 2) & 3) * 8 + ((s >> 4) & 1) * 4 + (s & 3));
    vtb[(long)(kvh * 128 + lane) * 4096 + spos]      = f2b(x1);
    vtb[(long)(kvh * 128 + lane + 64) * 4096 + spos] = f2b(x2);
    return;
  }
  float ss = x1 * x1 + x2 * x2;
#pragma unroll
  for (int m = 1; m < 64; m <<= 1) ss += __shfl_xor(ss, m);
  float rn = rsqrtf(ss * (1.0f / 128.0f) + 1.1920929e-07f);
  float c = cosT[s * 64 + lane], sn = sinT[s * 64 + lane];
  float x1n = x1 * rn, x2n = x2 * rn;
  float o1 = x1n * c + x2n * sn;
  float o2 = x2n * c - x1n * sn;
  if (h < 16) {
    const float scq = 0.08838834764831845f;  // 1/sqrt(128) folded into q
    ushort* dst = qb + ((long)h * 4096 + s) * 128;
    dst[lane] = f2b(o1 * scq);
    dst[lane + 64] = f2b(o2 * scq);
  } else {
    ushort* dst = kb + ((long)(h - 16) * 4096 + s) * 128;
    dst[lane] = f2b(o1);
    dst[lane + 64] = f2b(o2);
  }
}

// ------------- flash attention: 4 waves x 32 q-rows, LDS-staged K/V ---------
// (R16-verified structure + T5 setprio around QK^T and PV MFMA clusters:
//  2 independent blocks/CU at different loop phases = the m191 regime where
//  setprio pays on attn.)
__global__ __launch_bounds__(256, 2) void attn_k(const ushort* __restrict__ qb,
                                                 const ushort* __restrict__ kb,
                                                 const ushort* __restrict__ vtb,
                                                 ushort* __restrict__ yb) {
  __shared__ __align__(16) ushort lds[32768];  // buf{0,1} x (K 8192us | V 8192us)
  const int t = threadIdx.x;
  const int lane = t & 63, w = t >> 6;          // w = 0..3
  const int l15 = lane & 15, l4 = lane >> 4;
  const int q0 = ((int)gridDim.x - 1 - (int)blockIdx.x) * 128;  // heavy first
  const int h = blockIdx.y, kvh = h >> 2;
  const int qw = q0 + w * 32;
  const int qA = qw + l15, qB = qw + 16 + l15;
  const int lrd = l15 * 32 + ((l4 ^ ((l15 >> 1) & 3)) * 8);  // swizzled read

  bf16x8 qf0[4], qf1[4];
  {
    const ushort* QpA = qb + ((long)h * 4096 + qA) * 128 + l4 * 8;
    const ushort* QpB = qb + ((long)h * 4096 + qB) * 128 + l4 * 8;
#pragma unroll
    for (int c = 0; c < 4; ++c) {
      qf0[c] = *(const bf16x8*)(QpA + c * 32);
      qf1[c] = *(const bf16x8*)(QpB + c * 32);
    }
  }

  const ushort* Kg = kb + (long)kvh * 4096 * 128;
  const ushort* Vg = vtb + (long)kvh * 128 * 4096;

  int kb_lo = q0 - 1023; if (kb_lo < 0) kb_lo = 0; kb_lo &= ~63;
  const int nt = (q0 + 127 - kb_lo) / 64 + 1;

#define STAGE(kbs, b)                                                          \
  do {                                                                         \
    ushort* L_ = &lds[(b) * 16384];                                            \
    _Pragma("unroll") for (int c = 0; c < 8; ++c) {                            \
      const int us_ = t * 8 + c * 2048;                                        \
      if (c < 4) {                                                             \
        const int r_ = (us_ >> 5) & 63;                                        \
        const int cs_ = (((us_ >> 3) & 3) ^ ((r_ >> 1) & 3)) * 8;              \
        GLD_LDS16(Kg + (long)((kbs) + r_) * 128 + (us_ >> 11) * 32 + cs_,      \
                  L_ + us_);                                                   \
      } else {                                                                 \
        const int uv_ = us_ - 8192;                                            \
        const int r_ = (uv_ >> 5) & 127;                                       \
        const int cs_ = (((uv_ >> 3) & 3) ^ ((r_ >> 1) & 3)) * 8;              \
        GLD_LDS16(Vg + (long)r_ * 4096 + (kbs) + (uv_ >> 12) * 32 + cs_,       \
                  L_ + us_);                                                   \
      }                                                                        \
    }                                                                          \
  } while (0)

#define SMAX(sg, mr, lr, og, PA, PB)                                           \
  do {                                                                         \
    float mx = fmaxf(fmaxf(fmaxf(sg[0], sg[1]), fmaxf(sg[2], sg[3])),          \
                     fmaxf(fmaxf(sg[4], sg[5]), fmaxf(sg[6], sg[7])));         \
    mx = fmaxf(mx, fmaxf(fmaxf(fmaxf(sg[8], sg[9]), fmaxf(sg[10], sg[11])),    \
                         fmaxf(fmaxf(sg[12], sg[13]), fmaxf(sg[14], sg[15]))));\
    mx = fmaxf(mx, __shfl_xor(mx, 16));                                        \
    mx = fmaxf(mx, __shfl_xor(mx, 32));                                        \
    float mn;                                                                  \
    if (__all(mx <= (mr) + 8.0f)) {                                            \
      mn = (mr);                                                               \
    } else {                                                                   \
      mn = fmaxf((mr), mx);                                                    \
      const float corr = __expf((mr)-mn);                                      \
      (mr) = mn;                                                               \
      _Pragma("unroll") for (int db = 0; db < 8; ++db)                         \
          _Pragma("unroll") for (int r = 0; r < 4; ++r) og[db][r] *= corr;     \
      (lr) *= corr;                                                            \
    }                                                                          \
    float p[16];                                                               \
    _Pragma("unroll") for (int j = 0; j < 16; ++j) p[j] = __expf(sg[j] - mn);  \
    float ps = ((p[0] + p[1]) + (p[2] + p[3])) + ((p[4] + p[5]) + (p[6] + p[7])); \
    ps += ((p[8] + p[9]) + (p[10] + p[11])) + ((p[12] + p[13]) + (p[14] + p[15])); \
    ps += __shfl_xor(ps, 16);                                                  \
    ps += __shfl_xor(ps, 32);                                                  \
    (lr) += ps;                                                                \
    PA.u[0] = cvtpk(p[0], p[1]);   PA.u[1] = cvtpk(p[2], p[3]);                \
    PA.u[2] = cvtpk(p[4], p[5]);   PA.u[3] = cvtpk(p[6], p[7]);                \
    PB.u[0] = cvtpk(p[8], p[9]);   PB.u[1] = cvtpk(p[10], p[11]);              \
    PB.u[2] = cvtpk(p[12], p[13]); PB.u[3] = cvtpk(p[14], p[15]);              \
  } while (0)

  f32x4 o0[8] = {}, o1[8] = {};
  float mr0 = -1e30f, lr0 = 0.0f, mr1 = -1e30f, lr1 = 0.0f;

  STAGE(kb_lo, 0);

  for (int ti = 0; ti < nt; ++ti) {
    const int kbs = kb_lo + ti * 64;
    const int cur = ti & 1;
    const int tn = (ti + 1 < nt) ? ti + 1 : nt - 1;  // clamped (uniform count)
    STAGE(kb_lo + tn * 64, cur ^ 1);
    asm volatile("s_waitcnt vmcnt(8)" ::: "memory");  // own stage(t) resident
    __builtin_amdgcn_s_barrier();                     // all waves' stage(t) resident

    if (kbs <= qw + 31 && kbs + 63 >= qw - 1023) {  // wave-active
      const ushort* Kl = &lds[cur * 16384];
      const ushort* Vl = Kl + 8192;

      f32x4 sc0[4], sc1[4];
      __builtin_amdgcn_s_setprio(1);  // T5: favor MFMA cluster (m191 regime)
#pragma unroll
      for (int st = 0; st < 4; ++st) {
        sc0[st] = f32x4{0.f, 0.f, 0.f, 0.f};
        sc1[st] = f32x4{0.f, 0.f, 0.f, 0.f};
#pragma unroll
        for (int c = 0; c < 4; ++c) {
          bf16x8 kf = *(const bf16x8*)(Kl + c * 2048 + st * 512 + lrd);
          sc0[st] = mfma16(kf, qf0[c], sc0[st]);
          sc1[st] = mfma16(kf, qf1[c], sc1[st]);
        }
      }
      __builtin_amdgcn_s_setprio(0);

      float s0[16], s1[16];
      const bool fullA = (kbs + 64 <= qw) && (kbs >= qw - 1008);
      const bool fullB = (kbs + 64 <= qw + 16) && (kbs >= qw - 992);
      if (fullA) {
#pragma unroll
        for (int st = 0; st < 4; ++st)
#pragma unroll
          for (int r = 0; r < 4; ++r) s0[st * 4 + r] = sc0[st][r];
      } else {
#pragma unroll
        for (int st = 0; st < 4; ++st)
#pragma unroll
          for (int r = 0; r < 4; ++r) {
            const int ki = kbs + st * 16 + l4 * 4 + r;
            s0[st * 4 + r] = (ki <= qA && ki > qA - 1024) ? sc0[st][r] : -1e30f;
          }
      }
      if (fullB) {
#pragma unroll
        for (int st = 0; st < 4; ++st)
#pragma unroll
          for (int r = 0; r < 4; ++r) s1[st * 4 + r] = sc1[st][r];
      } else {
#pragma unroll
        for (int st = 0; st < 4; ++st)
#pragma unroll
          for (int r = 0; r < 4; ++r) {
            const int ki = kbs + st * 16 + l4 * 4 + r;
            s1[st * 4 + r] = (ki <= qB && ki > qB - 1024) ? sc1[st][r] : -1e30f;
          }
      }

      union { unsigned u[4]; bf16x8 v; } pa0, pb0, pa1, pb1;
      SMAX(s0, mr0, lr0, o0, pa0, pb0);
      SMAX(s1, mr1, lr1, o1, pa1, pb1);

      __builtin_amdgcn_s_setprio(1);  // T5: PV MFMA cluster
#pragma unroll
      for (int db = 0; db < 8; ++db) {
        bf16x8 v0 = *(const bf16x8*)(Vl + db * 512 + lrd);
        o0[db] = mfma16(v0, pa0.v, o0[db]);
        o1[db] = mfma16(v0, pa1.v, o1[db]);
        bf16x8 v1 = *(const bf16x8*)(Vl + 4096 + db * 512 + lrd);
        o0[db] = mfma16(v1, pb0.v, o0[db]);
        o1[db] = mfma16(v1, pb1.v, o1[db]);
      }
      __builtin_amdgcn_s_setprio(0);
    }
    __builtin_amdgcn_s_barrier();
  }

  const float i0 = 1.0f / lr0, i1 = 1.0f / lr1;
#pragma unroll
  for (int db = 0; db < 8; ++db)
#pragma unroll
    for (int r = 0; r < 4; ++r) {
      yb[(long)qA * 2048 + h * 128 + db * 16 + l4 * 4 + r] = f2b(o0[db][r] * i0);
      yb[(long)qB * 2048 + h * 128 + db * 16 + l4 * 4 + r] = f2b(o1[db][r] * i1);
    }
#undef STAGE
#undef SMAX
}

extern "C" void kernel_launch(void* const* d_in, const int* in_sizes, int n_in,
                              void* d_out, int out_size, void* d_ws, size_t ws_size,
                              hipStream_t stream) {
  (void)in_sizes; (void)n_in; (void)out_size; (void)ws_size;
  const float* x  = (const float*)d_in[0];
  const float* Wq = (const float*)d_in[1];
  const float* Wk = (const float*)d_in[2];
  const float* Wv = (const float*)d_in[3];
  const float* Wo = (const float*)d_in[4];
  const long S = 4096;
  ushort* ws   = (ushort*)d_ws;
  ushort* xb   = ws;                        // 4096*2048
  ushort* wqkv = xb + S * 2048;             // 3072*2048
  ushort* wob  = wqkv + 3072L * 2048;       // 2048*2048
  ushort* qkvb = wob + 2048L * 2048;        // 4096*3072
  ushort* qb   = qkvb + S * 3072;           // 16*4096*128
  ushort* kbuf = qb + S * 2048;             // 4*4096*128
  ushort* vtb  = kbuf + 4L * 4096 * 128;    // 4*128*4096 (key-permuted)
  ushort* yb   = vtb + 4L * 128 * 4096;     // 4096*2048
  float* cosT  = (float*)(yb + S * 2048);   // 4096*64
  float* sinT  = cosT + S * 64;             // 4096*64

  cast_all<<<dim3(18432), 256, 0, stream>>>(x, Wq, Wk, Wv, Wo, xb, wqkv, wob);
  gemm8p<128, 384, true><<<dim3(256), 512, 0, stream>>>(xb, wqkv, qkvb, 4096, 3072, 2048);
  rope_tables_k<<<dim3(4096), 64, 0, stream>>>(cosT, sinT);
  postproc_k<<<dim3(1024, 24), 256, 0, stream>>>(qkvb, cosT, sinT, qb, kbuf, vtb);
  attn_k<<<dim3(32, 16), 256, 0, stream>>>(qb, kbuf, vtb, yb);
  gemm8p<128, 256, false><<<dim3(256), 512, 0, stream>>>(yb, wob, d_out, 4096, 2048, 2048);
}

// Round 22
// 190.696 us; speedup vs baseline: 1.0043x; 1.0043x over previous
//
#include <hip/hip_runtime.h>

typedef short bf16x8 __attribute__((ext_vector_type(8)));
typedef float f32x4 __attribute__((ext_vector_type(4)));

__device__ __forceinline__ ushort f2b(float f) {
  union { float f; unsigned u; } v; v.f = f;
  unsigned r = v.u + 0x7FFF + ((v.u >> 16) & 1);
  return (ushort)(r >> 16);
}
__device__ __forceinline__ float b2f(ushort u) {
  union { unsigned u; float f; } v; v.u = ((unsigned)u) << 16;
  return v.f;
}
__device__ __forceinline__ unsigned cvtpk(float lo, float hi) {
  unsigned r;
  asm volatile("v_cvt_pk_bf16_f32 %0, %1, %2" : "=v"(r) : "v"(lo), "v"(hi));
  return r;
}
__device__ __forceinline__ f32x4 mfma16(bf16x8 a, bf16x8 b, f32x4 c) {
  return __builtin_amdgcn_mfma_f32_16x16x32_bf16(a, b, c, 0, 0, 0);
}

#define GLD_LDS16(g, l) \
  __builtin_amdgcn_global_load_lds((const __attribute__((address_space(1))) void*)(g), \
                                   (__attribute__((address_space(3))) void*)(l), 16, 0, 0)

// ---------------- fused fp32 -> bf16 cast (float4 units; R8-verified) -------
__global__ __launch_bounds__(256) void cast_all(const float* __restrict__ x,
                                                const float* __restrict__ wq,
                                                const float* __restrict__ wk,
                                                const float* __restrict__ wv,
                                                const float* __restrict__ wo,
                                                ushort* __restrict__ xb,
                                                ushort* __restrict__ wqkvb,
                                                ushort* __restrict__ wob) {
  const long i = (long)blockIdx.x * 256 + threadIdx.x;  // float4 index
  const float* src;
  ushort* dst;
  long j;
  if (i < 2097152) {            // x: 2097152 float4
    src = x; j = i; dst = xb;
  } else if (i < 3145728) {     // Wq: 1048576 float4
    src = wq; j = i - 2097152; dst = wqkvb;
  } else if (i < 3407872) {     // Wk: 262144 float4
    src = wk; j = i - 3145728; dst = wqkvb + 4194304;
  } else if (i < 3670016) {     // Wv: 262144 float4
    src = wv; j = i - 3407872; dst = wqkvb + 5242880;
  } else {                      // Wo: 1048576 float4 (total 4718592)
    src = wo; j = i - 3670016; dst = wob;
  }
  float4 f = ((const float4*)src)[j];
  ushort4 u;
  u.x = f2b(f.x); u.y = f2b(f.y); u.z = f2b(f.z); u.w = f2b(f.w);
  ((ushort4*)dst)[j] = u;
}

// ---------------- RoPE tables ----------------
__global__ void rope_tables_k(float* __restrict__ cosT, float* __restrict__ sinT) {
  int s = blockIdx.x, i = threadIdx.x;  // 64 threads
  float inv = powf(10000.0f, -(float)i * (1.0f / 64.0f));
  float f = (float)s * inv;
  cosT[s * 64 + i] = cosf(f);
  sinT[s * 64 + i] = sinf(f);
}

// =================== 8-phase pipelined GEMM (T2+T3+T4+T5) ===================
template <int BM, int BN, bool BF16OUT>
__global__ __launch_bounds__(512, 2) void gemm8p(const ushort* __restrict__ A,
                                                 const ushort* __restrict__ B,
                                                 void* __restrict__ Cout,
                                                 int M, int N, int K) {
  constexpr int AF = BM / 64;
  constexpr int BF = BN / 64;
  constexpr int MFR = BM / 32;
  constexpr int LA = BM / 128;
  constexpr int LB = BN / 128;
  constexpr int ASZ = BM * 32;
  constexpr int BSZ = BN * 32;
  constexpr int VMN = LA + 2 * LB;
  __shared__ __align__(16) ushort lds[4 * (ASZ + BSZ)];
  const int t = threadIdx.x;
  const int lane = t & 63, w = t >> 6;
  const int wr = w & 1, wc = w >> 1;
  const int l15 = lane & 15, l4 = lane >> 4;
  const int nbn = N / BN;
  const int nwg = (int)gridDim.x;
  int bid = (int)blockIdx.x;
  bid = (bid & 7) * (nwg >> 3) + (bid >> 3);  // XCD swizzle (nwg % 8 == 0)
  const long m0 = (long)(bid / nbn) * BM;
  const long n0 = (long)(bid % nbn) * BN;
  const int nk = K >> 6;
  const int rdl = l15 * 32 + ((l4 ^ ((l15 >> 1) & 3)) * 8);  // swizzled read

  f32x4 acc[MFR][BF] = {};
  bf16x8 af[AF], bf[BF];

#define STA(tile, ks)                                                          \
  do {                                                                         \
    const int tt_ = (tile) < nk ? (tile) : nk - 1;                             \
    _Pragma("unroll") for (int c = 0; c < LA; ++c) {                           \
      const int us_ = t * 8 + c * 4096;                                        \
      const int r_ = us_ >> 5;                                                 \
      const int cs_ = (((us_ >> 3) & 3) ^ ((r_ >> 1) & 3)) * 8;                \
      GLD_LDS16(A + (m0 + r_) * K + tt_ * 64 + (ks) * 32 + cs_,                \
                &lds[(((tile) & 1) * 2 + (ks)) * ASZ + us_]);                  \
    }                                                                          \
  } while (0)
#define STB(tile, ks)                                                          \
  do {                                                                         \
    const int tt_ = (tile) < nk ? (tile) : nk - 1;                             \
    _Pragma("unroll") for (int c = 0; c < LB; ++c) {                           \
      const int us_ = t * 8 + c * 4096;                                        \
      const int r_ = us_ >> 5;                                                 \
      const int cs_ = (((us_ >> 3) & 3) ^ ((r_ >> 1) & 3)) * 8;                \
      GLD_LDS16(B + (n0 + r_) * K + tt_ * 64 + (ks) * 32 + cs_,                \
                &lds[4 * ASZ + (((tile) & 1) * 2 + (ks)) * BSZ + us_]);        \
    }                                                                          \
  } while (0)
#define LDA8(slot, ks, mq)                                                     \
  _Pragma("unroll") for (int a = 0; a < AF; ++a)                               \
      af[a] = *(const bf16x8*)(&lds[((slot) * 2 + (ks)) * ASZ +                \
                                    (wr * MFR + (mq) * AF + a) * 512 + rdl]);
#define LDB8(slot, ks)                                                         \
  _Pragma("unroll") for (int b = 0; b < BF; ++b)                               \
      bf[b] = *(const bf16x8*)(&lds[4 * ASZ + ((slot) * 2 + (ks)) * BSZ +      \
                                    (wc * BF + b) * 512 + rdl]);
#define VMW()                                                                  \
  do {                                                                         \
    if constexpr (VMN == 7)                                                    \
      asm volatile("s_waitcnt vmcnt(7)" ::: "memory");                         \
    else if constexpr (VMN == 6)                                               \
      asm volatile("s_waitcnt vmcnt(6)" ::: "memory");                         \
    else                                                                       \
      asm volatile("s_waitcnt vmcnt(5)" ::: "memory");                         \
  } while (0)
#define BARMM(mq)                                                              \
  do {                                                                         \
    __builtin_amdgcn_s_barrier();                                              \
    asm volatile("s_waitcnt lgkmcnt(0)" ::: "memory");                         \
    __builtin_amdgcn_sched_barrier(0);                                         \
    __builtin_amdgcn_s_setprio(1);                                             \
    _Pragma("unroll") for (int a = 0; a < AF; ++a)                             \
        _Pragma("unroll") for (int b = 0; b < BF; ++b)                         \
            acc[(mq) * AF + a][b] = mfma16(af[a], bf[b], acc[(mq) * AF + a][b]); \
    __builtin_amdgcn_s_setprio(0);                                             \
    __builtin_amdgcn_s_barrier();                                              \
  } while (0)

  STA(0, 0); STB(0, 0); STA(0, 1); STB(0, 1);
  STA(1, 0); STB(1, 0); STB(1, 1);
  VMW();
  __builtin_amdgcn_s_barrier();

  for (int i = 0; i < (nk >> 1); ++i) {
    const int t1 = 2 * i + 1, t2 = 2 * i + 2, t3 = 2 * i + 3;
    LDA8(0, 0, 0); LDB8(0, 0); STA(t1, 1);          BARMM(0);  // ph1
    LDA8(0, 0, 1);             STB(t2, 0);          BARMM(1);  // ph2
    LDA8(0, 1, 0); LDB8(0, 1); STA(t2, 0);          BARMM(0);  // ph3
    LDA8(0, 1, 1);             STB(t2, 1); VMW();   BARMM(1);  // ph4
    LDA8(1, 0, 0); LDB8(1, 0); STA(t2, 1);          BARMM(0);  // ph5
    LDA8(1, 0, 1);             STB(t3, 0);          BARMM(1);  // ph6
    LDA8(1, 1, 0); LDB8(1, 1); STA(t3, 0);          BARMM(0);  // ph7
    LDA8(1, 1, 1);             STB(t3, 1); VMW();   BARMM(1);  // ph8
  }
  asm volatile("s_waitcnt vmcnt(0)" ::: "memory");

#pragma unroll
  for (int m = 0; m < MFR; ++m) {
#pragma unroll
    for (int n = 0; n < BF; ++n) {
      long mrow = m0 + wr * (BM / 2) + m * 16 + l4 * 4;
      long ncol = n0 + wc * (BN / 4) + n * 16 + l15;
#pragma unroll
      for (int r = 0; r < 4; ++r) {
        if constexpr (BF16OUT)
          ((ushort*)Cout)[(mrow + r) * N + ncol] = f2b(acc[m][n][r]);
        else
          ((float*)Cout)[(mrow + r) * N + ncol] = acc[m][n][r];
      }
    }
  }
#undef STA
#undef STB
#undef LDA8
#undef LDB8
#undef VMW
#undef BARMM
}

// ---------------- RMSnorm + RoPE + layout (q,k) / cast+transpose (v) --------
__global__ __launch_bounds__(256) void postproc_k(const ushort* __restrict__ qkvb,
                                                  const float* __restrict__ cosT,
                                                  const float* __restrict__ sinT,
                                                  ushort* __restrict__ qb,
                                                  ushort* __restrict__ kb,
                                                  ushort* __restrict__ vtb) {
  const int lane = threadIdx.x & 63;
  const int s = blockIdx.x * 4 + (threadIdx.x >> 6);
  const int h = blockIdx.y;
  const int colbase = (h < 16) ? h * 128 : (h < 20 ? 2048 + (h - 16) * 128
                                                   : 2560 + (h - 20) * 128);
  const ushort* row = qkvb + (long)s * 3072 + colbase;
  float x1 = b2f(row[lane]), x2 = b2f(row[lane + 64]);
  if (h >= 20) {  // V: cast + transpose to [kvh][128][S-permuted]
    int kvh = h - 20;
    int spos = (s & ~31) | (((s >> 2) & 3) * 8 + ((s >> 4) & 1) * 4 + (s & 3));
    vtb[(long)(kvh * 128 + lane) * 4096 + spos]      = f2b(x1);
    vtb[(long)(kvh * 128 + lane + 64) * 4096 + spos] = f2b(x2);
    return;
  }
  float ss = x1 * x1 + x2 * x2;
#pragma unroll
  for (int m = 1; m < 64; m <<= 1) ss += __shfl_xor(ss, m);
  float rn = rsqrtf(ss * (1.0f / 128.0f) + 1.1920929e-07f);
  float c = cosT[s * 64 + lane], sn = sinT[s * 64 + lane];
  float x1n = x1 * rn, x2n = x2 * rn;
  float o1 = x1n * c + x2n * sn;
  float o2 = x2n * c - x1n * sn;
  if (h < 16) {
    const float scq = 0.08838834764831845f;  // 1/sqrt(128) folded into q
    ushort* dst = qb + ((long)h * 4096 + s) * 128;
    dst[lane] = f2b(o1 * scq);
    dst[lane + 64] = f2b(o2 * scq);
  } else {
    ushort* dst = kb + ((long)(h - 16) * 4096 + s) * 128;
    dst[lane] = f2b(o1);
    dst[lane + 64] = f2b(o2);
  }
}

// ------------- flash attention: 4 waves x 32 q-rows, LDS-staged K/V ---------
// (R16/R18/R20-verified: counted-vmcnt double-barrier loop, chunk-swizzled
//  LDS, in-register swapped-QK^T softmax, defer-max. 190.99 us total, 3x
//  reproduced. setprio variant (R21) was null; reg-staged/direct/32-key/
//  64-row variants (R12/R15/R17/R19) all regressed.)
__global__ __launch_bounds__(256, 2) void attn_k(const ushort* __restrict__ qb,
                                                 const ushort* __restrict__ kb,
                                                 const ushort* __restrict__ vtb,
                                                 ushort* __restrict__ yb) {
  __shared__ __align__(16) ushort lds[32768];  // buf{0,1} x (K 8192us | V 8192us)
  const int t = threadIdx.x;
  const int lane = t & 63, w = t >> 6;          // w = 0..3
  const int l15 = lane & 15, l4 = lane >> 4;
  const int q0 = ((int)gridDim.x - 1 - (int)blockIdx.x) * 128;  // heavy first
  const int h = blockIdx.y, kvh = h >> 2;
  const int qw = q0 + w * 32;
  const int qA = qw + l15, qB = qw + 16 + l15;
  const int lrd = l15 * 32 + ((l4 ^ ((l15 >> 1) & 3)) * 8);  // swizzled read

  bf16x8 qf0[4], qf1[4];
  {
    const ushort* QpA = qb + ((long)h * 4096 + qA) * 128 + l4 * 8;
    const ushort* QpB = qb + ((long)h * 4096 + qB) * 128 + l4 * 8;
#pragma unroll
    for (int c = 0; c < 4; ++c) {
      qf0[c] = *(const bf16x8*)(QpA + c * 32);
      qf1[c] = *(const bf16x8*)(QpB + c * 32);
    }
  }

  const ushort* Kg = kb + (long)kvh * 4096 * 128;
  const ushort* Vg = vtb + (long)kvh * 128 * 4096;

  int kb_lo = q0 - 1023; if (kb_lo < 0) kb_lo = 0; kb_lo &= ~63;
  const int nt = (q0 + 127 - kb_lo) / 64 + 1;

#define STAGE(kbs, b)                                                          \
  do {                                                                         \
    ushort* L_ = &lds[(b) * 16384];                                            \
    _Pragma("unroll") for (int c = 0; c < 8; ++c) {                            \
      const int us_ = t * 8 + c * 2048;                                        \
      if (c < 4) {                                                             \
        const int r_ = (us_ >> 5) & 63;                                        \
        const int cs_ = (((us_ >> 3) & 3) ^ ((r_ >> 1) & 3)) * 8;              \
        GLD_LDS16(Kg + (long)((kbs) + r_) * 128 + (us_ >> 11) * 32 + cs_,      \
                  L_ + us_);                                                   \
      } else {                                                                 \
        const int uv_ = us_ - 8192;                                            \
        const int r_ = (uv_ >> 5) & 127;                                       \
        const int cs_ = (((uv_ >> 3) & 3) ^ ((r_ >> 1) & 3)) * 8;              \
        GLD_LDS16(Vg + (long)r_ * 4096 + (kbs) + (uv_ >> 12) * 32 + cs_,       \
                  L_ + us_);                                                   \
      }                                                                        \
    }                                                                          \
  } while (0)

#define SMAX(sg, mr, lr, og, PA, PB)                                           \
  do {                                                                         \
    float mx = fmaxf(fmaxf(fmaxf(sg[0], sg[1]), fmaxf(sg[2], sg[3])),          \
                     fmaxf(fmaxf(sg[4], sg[5]), fmaxf(sg[6], sg[7])));         \
    mx = fmaxf(mx, fmaxf(fmaxf(fmaxf(sg[8], sg[9]), fmaxf(sg[10], sg[11])),    \
                         fmaxf(fmaxf(sg[12], sg[13]), fmaxf(sg[14], sg[15]))));\
    mx = fmaxf(mx, __shfl_xor(mx, 16));                                        \
    mx = fmaxf(mx, __shfl_xor(mx, 32));                                        \
    float mn;                                                                  \
    if (__all(mx <= (mr) + 8.0f)) {                                            \
      mn = (mr);                                                               \
    } else {                                                                   \
      mn = fmaxf((mr), mx);                                                    \
      const float corr = __expf((mr)-mn);                                      \
      (mr) = mn;                                                               \
      _Pragma("unroll") for (int db = 0; db < 8; ++db)                         \
          _Pragma("unroll") for (int r = 0; r < 4; ++r) og[db][r] *= corr;     \
      (lr) *= corr;                                                            \
    }                                                                          \
    float p[16];                                                               \
    _Pragma("unroll") for (int j = 0; j < 16; ++j) p[j] = __expf(sg[j] - mn);  \
    float ps = ((p[0] + p[1]) + (p[2] + p[3])) + ((p[4] + p[5]) + (p[6] + p[7])); \
    ps += ((p[8] + p[9]) + (p[10] + p[11])) + ((p[12] + p[13]) + (p[14] + p[15])); \
    ps += __shfl_xor(ps, 16);                                                  \
    ps += __shfl_xor(ps, 32);                                                  \
    (lr) += ps;                                                                \
    PA.u[0] = cvtpk(p[0], p[1]);   PA.u[1] = cvtpk(p[2], p[3]);                \
    PA.u[2] = cvtpk(p[4], p[5]);   PA.u[3] = cvtpk(p[6], p[7]);                \
    PB.u[0] = cvtpk(p[8], p[9]);   PB.u[1] = cvtpk(p[10], p[11]);              \
    PB.u[2] = cvtpk(p[12], p[13]); PB.u[3] = cvtpk(p[14], p[15]);              \
  } while (0)

  f32x4 o0[8] = {}, o1[8] = {};
  float mr0 = -1e30f, lr0 = 0.0f, mr1 = -1e30f, lr1 = 0.0f;

  STAGE(kb_lo, 0);

  for (int ti = 0; ti < nt; ++ti) {
    const int kbs = kb_lo + ti * 64;
    const int cur = ti & 1;
    const int tn = (ti + 1 < nt) ? ti + 1 : nt - 1;  // clamped (uniform count)
    STAGE(kb_lo + tn * 64, cur ^ 1);
    asm volatile("s_waitcnt vmcnt(8)" ::: "memory");  // own stage(t) resident
    __builtin_amdgcn_s_barrier();                     // all waves' stage(t) resident

    if (kbs <= qw + 31 && kbs + 63 >= qw - 1023) {  // wave-active
      const ushort* Kl = &lds[cur * 16384];
      const ushort* Vl = Kl + 8192;

      f32x4 sc0[4], sc1[4];
#pragma unroll
      for (int st = 0; st < 4; ++st) {
        sc0[st] = f32x4{0.f, 0.f, 0.f, 0.f};
        sc1[st] = f32x4{0.f, 0.f, 0.f, 0.f};
#pragma unroll
        for (int c = 0; c < 4; ++c) {
          bf16x8 kf = *(const bf16x8*)(Kl + c * 2048 + st * 512 + lrd);
          sc0[st] = mfma16(kf, qf0[c], sc0[st]);
          sc1[st] = mfma16(kf, qf1[c], sc1[st]);
        }
      }

      float s0[16], s1[16];
      const bool fullA = (kbs + 64 <= qw) && (kbs >= qw - 1008);
      const bool fullB = (kbs + 64 <= qw + 16) && (kbs >= qw - 992);
      if (fullA) {
#pragma unroll
        for (int st = 0; st < 4; ++st)
#pragma unroll
          for (int r = 0; r < 4; ++r) s0[st * 4 + r] = sc0[st][r];
      } else {
#pragma unroll
        for (int st = 0; st < 4; ++st)
#pragma unroll
          for (int r = 0; r < 4; ++r) {
            const int ki = kbs + st * 16 + l4 * 4 + r;
            s0[st * 4 + r] = (ki <= qA && ki > qA - 1024) ? sc0[st][r] : -1e30f;
          }
      }
      if (fullB) {
#pragma unroll
        for (int st = 0; st < 4; ++st)
#pragma unroll
          for (int r = 0; r < 4; ++r) s1[st * 4 + r] = sc1[st][r];
      } else {
#pragma unroll
        for (int st = 0; st < 4; ++st)
#pragma unroll
          for (int r = 0; r < 4; ++r) {
            const int ki = kbs + st * 16 + l4 * 4 + r;
            s1[st * 4 + r] = (ki <= qB && ki > qB - 1024) ? sc1[st][r] : -1e30f;
          }
      }

      union { unsigned u[4]; bf16x8 v; } pa0, pb0, pa1, pb1;
      SMAX(s0, mr0, lr0, o0, pa0, pb0);
      SMAX(s1, mr1, lr1, o1, pa1, pb1);

#pragma unroll
      for (int db = 0; db < 8; ++db) {
        bf16x8 v0 = *(const bf16x8*)(Vl + db * 512 + lrd);
        o0[db] = mfma16(v0, pa0.v, o0[db]);
        o1[db] = mfma16(v0, pa1.v, o1[db]);
        bf16x8 v1 = *(const bf16x8*)(Vl + 4096 + db * 512 + lrd);
        o0[db] = mfma16(v1, pb0.v, o0[db]);
        o1[db] = mfma16(v1, pb1.v, o1[db]);
      }
    }
    __builtin_amdgcn_s_barrier();
  }

  const float i0 = 1.0f / lr0, i1 = 1.0f / lr1;
#pragma unroll
  for (int db = 0; db < 8; ++db)
#pragma unroll
    for (int r = 0; r < 4; ++r) {
      yb[(long)qA * 2048 + h * 128 + db * 16 + l4 * 4 + r] = f2b(o0[db][r] * i0);
      yb[(long)qB * 2048 + h * 128 + db * 16 + l4 * 4 + r] = f2b(o1[db][r] * i1);
    }
#undef STAGE
#undef SMAX
}

extern "C" void kernel_launch(void* const* d_in, const int* in_sizes, int n_in,
                              void* d_out, int out_size, void* d_ws, size_t ws_size,
                              hipStream_t stream) {
  (void)in_sizes; (void)n_in; (void)out_size; (void)ws_size;
  const float* x  = (const float*)d_in[0];
  const float* Wq = (const float*)d_in[1];
  const float* Wk = (const float*)d_in[2];
  const float* Wv = (const float*)d_in[3];
  const float* Wo = (const float*)d_in[4];
  const long S = 4096;
  ushort* ws   = (ushort*)d_ws;
  ushort* xb   = ws;                        // 4096*2048
  ushort* wqkv = xb + S * 2048;             // 3072*2048
  ushort* wob  = wqkv + 3072L * 2048;       // 2048*2048
  ushort* qkvb = wob + 2048L * 2048;        // 4096*3072
  ushort* qb   = qkvb + S * 3072;           // 16*4096*128
  ushort* kbuf = qb + S * 2048;             // 4*4096*128
  ushort* vtb  = kbuf + 4L * 4096 * 128;    // 4*128*4096 (key-permuted)
  ushort* yb   = vtb + 4L * 128 * 4096;     // 4096*2048
  float* cosT  = (float*)(yb + S * 2048);   // 4096*64
  float* sinT  = cosT + S * 64;             // 4096*64

  cast_all<<<dim3(18432), 256, 0, stream>>>(x, Wq, Wk, Wv, Wo, xb, wqkv, wob);
  gemm8p<128, 384, true><<<dim3(256), 512, 0, stream>>>(xb, wqkv, qkvb, 4096, 3072, 2048);
  rope_tables_k<<<dim3(4096), 64, 0, stream>>>(cosT, sinT);
  postproc_k<<<dim3(1024, 24), 256, 0, stream>>>(qkvb, cosT, sinT, qb, kbuf, vtb);
  attn_k<<<dim3(32, 16), 256, 0, stream>>>(qb, kbuf, vtb, yb);
  gemm8p<128, 256, false><<<dim3(256), 512, 0, stream>>>(yb, wob, d_out, 4096, 2048, 2048);
}